// Round 5
// baseline (1651.040 us; speedup 1.0000x reference)
//
#include <hip/hip_runtime.h>
#include <math.h>

#define Bsz 512
#define Fsz 64
#define Hsz 256
#define TSTEPS 128
#define G3 768

#define BG 16            // batch groups (32 rows each)
#define HB 16            // hidden-slice blocks (16 cols x 3 gates)
#define NBLK 256
#define NTHR 256

typedef float f32x4 __attribute__((ext_vector_type(4)));
typedef short s16x8 __attribute__((ext_vector_type(8)));
typedef unsigned int u32x4 __attribute__((ext_vector_type(4)));

#define MF(a,b,c) __builtin_amdgcn_mfma_f32_16x16x32_bf16(a,b,c,0,0,0)

static __device__ __forceinline__ unsigned short bf16_rne(float f){
    union { float f; unsigned u; } v; v.f = f;
    return (unsigned short)((v.u + 0x7FFFu + ((v.u >> 16) & 1u)) >> 16);
}
static __device__ __forceinline__ float bf16_to_f(unsigned short h){
    union { unsigned u; float f; } v; v.u = ((unsigned)h) << 16; return v.f;
}
static __device__ __forceinline__ void split8(const float* p, s16x8& hi, s16x8& lo){
    union { s16x8 v; unsigned short e[8]; } H, L;
    #pragma unroll
    for (int t = 0; t < 8; ++t){
        float f = p[t];
        unsigned short h = bf16_rne(f);
        H.e[t] = h; L.e[t] = bf16_rne(f - bf16_to_f(h));
    }
    hi = H.v; lo = L.v;
}
static __device__ __forceinline__ void split8f(f32x4 a, f32x4 b, s16x8& hi, s16x8& lo){
    union { s16x8 v; unsigned short e[8]; } H, L;
    float fv[8] = {a[0],a[1],a[2],a[3],b[0],b[1],b[2],b[3]};
    #pragma unroll
    for (int t = 0; t < 8; ++t){
        unsigned short h = bf16_rne(fv[t]);
        H.e[t] = h; L.e[t] = bf16_rne(fv[t] - bf16_to_f(h));
    }
    hi = H.v; lo = L.v;
}
// unpack 8 packed u32 (hi16|lo16 bf16 per element) -> hi/lo s16x8 fragments
static __device__ __forceinline__ void unpack8(u32x4 a, u32x4 b, s16x8& hi, s16x8& lo){
    union { s16x8 v; unsigned u[4]; } H, L;
    unsigned w[8] = {a[0],a[1],a[2],a[3],b[0],b[1],b[2],b[3]};
    #pragma unroll
    for (int d = 0; d < 4; ++d){
        unsigned w0 = w[2*d], w1 = w[2*d+1];
        H.u[d] = (w0 >> 16) | (w1 & 0xFFFF0000u);
        L.u[d] = (w0 & 0xFFFFu) | (w1 << 16);
    }
    hi = H.v; lo = L.v;
}
static __device__ __forceinline__ float sigmoidf_(float v){ return 1.0f/(1.0f + expf(-v)); }

// ---- MALL-coherent (cache-bypass) ops: sc0 sc1 = skip L1+L2 ----
__device__ __forceinline__ u32x4 load_sys_b128u(const unsigned* p){
    u32x4 r;
    asm volatile("global_load_dwordx4 %0, %1, off sc0 sc1" : "=v"(r) : "v"(p) : "memory");
    return r;
}
__device__ __forceinline__ unsigned load_sys_b32u_async(const unsigned* p){
    unsigned r;
    asm volatile("global_load_dword %0, %1, off sc0 sc1" : "=v"(r) : "v"(p) : "memory");
    return r;
}
__device__ __forceinline__ void store_sys_b32u(unsigned* p, unsigned v){
    asm volatile("global_store_dword %0, %1, off sc0 sc1" :: "v"(p), "v"(v) : "memory");
}
__device__ __forceinline__ int load_sys_i32(const int* p){
    int r;
    asm volatile("global_load_dword %0, %1, off sc0 sc1\n\ts_waitcnt vmcnt(0)"
                 : "=v"(r) : "v"(p) : "memory");
    return r;
}
__device__ __forceinline__ void waitcnt0(){ asm volatile("s_waitcnt vmcnt(0)" ::: "memory"); }
__device__ __forceinline__ void regbar4(u32x4& v){ asm volatile("" : "+v"(v)); }
__device__ __forceinline__ void regbar1(unsigned& v){ asm volatile("" : "+v"(v)); }

// all 64 lanes poll 32 tags (2 lanes per tag) until all >= target
__device__ __forceinline__ void poll_ge(const int* tp, int target){
    int v;
    do { v = load_sys_i32(tp); } while (!__all(v >= target));
}

// ---------------- setup: M = dec_Wih@reg_W, cfold = dec_Wih@reg_b + dec_bih,
// ---------------- gi0 = x[:,127,:]@dec_Wih.T + dec_bih
extern "C" __global__ void gru_setup(const float* __restrict__ x,
                                     const float* __restrict__ dWih,
                                     const float* __restrict__ dbih,
                                     const float* __restrict__ regW,
                                     const float* __restrict__ regb,
                                     float* __restrict__ Mw,
                                     float* __restrict__ cfold,
                                     float* __restrict__ gi0)
{
    int idx = blockIdx.x*blockDim.x + threadIdx.x;
    if (idx < G3*Hsz) {
        int g = idx >> 8, j = idx & 255;
        float a = 0.f;
        #pragma unroll 8
        for (int f = 0; f < Fsz; ++f) a += dWih[g*Fsz + f]*regW[f*Hsz + j];
        Mw[idx] = a;
    } else if (idx < G3*Hsz + G3) {
        int g = idx - G3*Hsz;
        float a = dbih[g];
        #pragma unroll 8
        for (int f = 0; f < Fsz; ++f) a += dWih[g*Fsz + f]*regb[f];
        cfold[g] = a;
    } else {
        int e = idx - (G3*Hsz + G3);
        if (e < Bsz*G3) {
            int b = e / G3, g = e - b*G3;
            const float* xp = x + (size_t)b*(256*64) + 127*64;
            float a = dbih[g];
            #pragma unroll 8
            for (int f = 0; f < Fsz; ++f) a += xp[f]*dWih[g*Fsz + f];
            gi0[e] = a;
        }
    }
}

// ---------------- persistent GRU kernel (barrier-free step loop) ----------------
extern "C" __global__ void __launch_bounds__(NTHR, 1)
gru_persistent(const float* __restrict__ x,
               const float* __restrict__ eWih, const float* __restrict__ eWhh,
               const float* __restrict__ ebih, const float* __restrict__ ebhh,
               const float* __restrict__ dWhh, const float* __restrict__ dbhh,
               const float* __restrict__ Mw,   const float* __restrict__ cfold,
               const float* __restrict__ gi0,  const float* __restrict__ regW,
               const float* __restrict__ regb,
               unsigned* __restrict__ hbuf, int* __restrict__ tags,
               float* __restrict__ out)
{
    __shared__ float s_part[4][4][256];   // [m*2+par][slot R,Z,Ni,Nh][lane*4+j]
    __shared__ float s_bias[128];
    __shared__ unsigned short s_rw[2][8][64][8];  // regW frags [hi/lo][q8][lane][8]
    __shared__ int s_flag[2];             // per-m monotone handoff counter

    const int tid  = threadIdx.x;
    const int wv   = tid >> 6;
    const int m    = wv & 1;       // batch half: rows m*16..m*16+15 of the bg slice
    const int kh   = wv >> 1;      // k half: [kh*128, kh*128+128)
    const int lane = tid & 63;
    const int quad = lane >> 4;
    const int lcol = lane & 15;
    const int bg   = blockIdx.x >> 4;
    const int hb   = blockIdx.x & 15;
    const int hcol = hb*16 + lcol;
    const int* mytags = tags + bg*32;
    const f32x4 z4 = {0.f,0.f,0.f,0.f};

    // ---- encoder weight fragments (registers, static over 128 steps) ----
    s16x8 wfh[3][4], wfl[3][4];    // Whh b-frags: [gate][q], k = kh*128 + q*32 + quad*8
    s16x8 ufh[3], ufl[3];          // Wih b-frags: k = kh*32 + quad*8
    #pragma unroll
    for (int g3 = 0; g3 < 3; ++g3){
        #pragma unroll
        for (int q = 0; q < 4; ++q)
            split8(eWhh + (size_t)(g3*256 + hcol)*256 + kh*128 + q*32 + quad*8,
                   wfh[g3][q], wfl[g3][q]);
        split8(eWih + (size_t)(g3*256 + hcol)*64 + kh*32 + quad*8, ufh[g3], ufl[g3]);
    }
    if (tid == 0){ s_flag[0] = 0; s_flag[1] = 0; }
    if (tid < 16){
        int c = hb*16 + tid;
        s_bias[tid]    = ebih[c]     + ebhh[c];      // R
        s_bias[16+tid] = ebih[256+c] + ebhh[256+c];  // Z
        s_bias[32+tid] = ebih[512+c];                // Ni
        s_bias[48+tid] = ebhh[512+c];                // Nh
    }
    __syncthreads();

    // =================== ENCODER (g = 0..127) ===================
    for (int g = 0; g < TSTEPS; ++g){
        const unsigned* hin  = hbuf + (size_t)(g & 1)*Bsz*Hsz;
        unsigned* hout = hbuf + (size_t)((g + 1) & 1)*Bsz*Hsz;

        f32x4 accR = z4, accZ = z4, accNi = z4, accNh = z4;

        // ---- x-GEMM (independent of h: before the poll) ----
        {
            const float* xp = x + (size_t)(bg*32 + m*16 + lcol)*(256*64)
                              + (size_t)g*64 + kh*32 + quad*8;
            f32x4 xa = *(const f32x4*)xp;
            f32x4 xb = *(const f32x4*)(xp + 4);
            s16x8 xh, xl; split8f(xa, xb, xh, xl);
            accR  = MF(xh, ufh[0], accR);  accR  = MF(xh, ufl[0], accR);  accR  = MF(xl, ufh[0], accR);
            accZ  = MF(xh, ufh[1], accZ);  accZ  = MF(xh, ufl[1], accZ);  accZ  = MF(xl, ufh[1], accZ);
            accNi = MF(xh, ufh[2], accNi); accNi = MF(xh, ufl[2], accNi); accNi = MF(xl, ufh[2], accNi);
        }

        if (g > 0) poll_ge(mytags + (lane & 31), g);

        // ---- direct global A-frag loads (MALL) ----
        const unsigned* hrow = hin + (size_t)(bg*32 + m*16 + lcol)*256;
        u32x4 A[8];
        #pragma unroll
        for (int q = 0; q < 4; ++q){
            int ko = kh*128 + q*32 + quad*8;
            A[2*q]   = load_sys_b128u(hrow + ko);
            A[2*q+1] = load_sys_b128u(hrow + ko + 4);
        }
        unsigned HO[4];
        if (kh == 0){
            #pragma unroll
            for (int j = 0; j < 4; ++j)
                HO[j] = load_sys_b32u_async(hin + (size_t)(bg*32 + m*16 + quad*4 + j)*256 + hcol);
        }
        waitcnt0();
        #pragma unroll
        for (int q = 0; q < 8; ++q) regbar4(A[q]);
        if (kh == 0){ regbar1(HO[0]); regbar1(HO[1]); regbar1(HO[2]); regbar1(HO[3]); }

        s16x8 ah[4], al[4];
        #pragma unroll
        for (int q = 0; q < 4; ++q) unpack8(A[2*q], A[2*q+1], ah[q], al[q]);

        // ---- gh MFMA (this wave's k-half) ----
        #pragma unroll
        for (int q = 0; q < 4; ++q){
            s16x8 H = ah[q], L = al[q];
            accR  = MF(H, wfh[0][q], accR);  accR  = MF(H, wfl[0][q], accR);  accR  = MF(L, wfh[0][q], accR);
            accZ  = MF(H, wfh[1][q], accZ);  accZ  = MF(H, wfl[1][q], accZ);  accZ  = MF(L, wfh[1][q], accZ);
            accNh = MF(H, wfh[2][q], accNh); accNh = MF(H, wfl[2][q], accNh); accNh = MF(L, wfh[2][q], accNh);
        }

        const int par = g & 1;
        if (kh == 1){
            float* pb = &s_part[m*2 + par][0][0] + lane*4;
            *(f32x4*)(pb)       = accR;
            *(f32x4*)(pb + 256) = accZ;
            *(f32x4*)(pb + 512) = accNi;
            *(f32x4*)(pb + 768) = accNh;
            if (lane == 0)
                __hip_atomic_store(&s_flag[m], g + 1, __ATOMIC_RELEASE, __HIP_MEMORY_SCOPE_WORKGROUP);
        } else {
            while (__hip_atomic_load(&s_flag[m], __ATOMIC_ACQUIRE, __HIP_MEMORY_SCOPE_WORKGROUP) < g + 1) {}
            const float* pb = &s_part[m*2 + par][0][0] + lane*4;
            accR  += *(const f32x4*)(pb);
            accZ  += *(const f32x4*)(pb + 256);
            accNi += *(const f32x4*)(pb + 512);
            accNh += *(const f32x4*)(pb + 768);
            #pragma unroll
            for (int j = 0; j < 4; ++j){
                float R = sigmoidf_(accR[j] + s_bias[lcol]);
                float Z = sigmoidf_(accZ[j] + s_bias[16 + lcol]);
                float N = tanhf(accNi[j] + s_bias[32 + lcol] + R*(accNh[j] + s_bias[48 + lcol]));
                float hold = bf16_to_f((unsigned short)(HO[j] >> 16))
                           + bf16_to_f((unsigned short)(HO[j] & 0xFFFFu));
                float hv = (1.0f - Z)*N + Z*hold;
                unsigned short p1 = bf16_rne(hv);
                unsigned short p0 = bf16_rne(hv - bf16_to_f(p1));
                store_sys_b32u(hout + (size_t)(bg*32 + m*16 + quad*4 + j)*256 + hcol,
                               (((unsigned)p1) << 16) | (unsigned)p0);
            }
            waitcnt0();
            if (lane == 0)
                store_sys_b32u((unsigned*)(tags + bg*32 + hb*2 + m), (unsigned)(g + 1));
        }
    }

    // ---- decoder weight fragments + biases ----
    __syncthreads();
    s16x8 mfh[3][4], mfl[3][4];
    #pragma unroll
    for (int g3 = 0; g3 < 3; ++g3)
        #pragma unroll
        for (int q = 0; q < 4; ++q){
            split8(dWhh + (size_t)(g3*256 + hcol)*256 + kh*128 + q*32 + quad*8,
                   wfh[g3][q], wfl[g3][q]);
            split8(Mw   + (size_t)(g3*256 + hcol)*256 + kh*128 + q*32 + quad*8,
                   mfh[g3][q], mfl[g3][q]);
        }
    if (wv == 2){   // stage regW fragments to LDS (same per-lane frag for wv2/wv3)
        #pragma unroll
        for (int q8 = 0; q8 < 8; ++q8){
            s16x8 rh, rl;
            split8(regW + (size_t)(hb*4 + (lcol & 3))*256 + q8*32 + quad*8, rh, rl);
            *(s16x8*)&s_rw[0][q8][lane][0] = rh;
            *(s16x8*)&s_rw[1][q8][lane][0] = rl;
        }
    }
    if (tid < 16){
        int c = hb*16 + tid;
        s_bias[tid]      = cfold[c]       + dbhh[c];      // R (i>0)
        s_bias[16+tid]   = cfold[256+c]   + dbhh[256+c];  // Z (i>0)
        s_bias[32+tid]   = cfold[512+c];                  // Ni (i>0)
        s_bias[48+tid]   = dbhh[512+c];                   // Nh
        s_bias[64+tid]   = dbhh[c];                       // R (i==0)
        s_bias[80+tid]   = dbhh[256+c];                   // Z (i==0)
    }
    if (tid < 4) s_bias[96 + tid] = regb[hb*4 + tid];
    __syncthreads();

    // =================== DECODER (g = 128..255) ===================
    for (int i = 0; i < TSTEPS; ++i){
        const int g = TSTEPS + i;
        const unsigned* hin  = hbuf + (size_t)(g & 1)*Bsz*Hsz;
        unsigned* hout = hbuf + (size_t)((g + 1) & 1)*Bsz*Hsz;

        f32x4 accR = z4, accZ = z4, accNi = z4, accNh = z4;

        poll_ge(mytags + (lane & 31), g);

        const unsigned* hrow = hin + (size_t)(bg*32 + m*16 + lcol)*256;
        u32x4 A[8], B2[8];
        #pragma unroll
        for (int q = 0; q < 4; ++q){
            int ko = kh*128 + q*32 + quad*8;
            A[2*q]   = load_sys_b128u(hrow + ko);
            A[2*q+1] = load_sys_b128u(hrow + ko + 4);
        }
        unsigned HO[4];
        if (kh == 0){
            #pragma unroll
            for (int j = 0; j < 4; ++j)
                HO[j] = load_sys_b32u_async(hin + (size_t)(bg*32 + m*16 + quad*4 + j)*256 + hcol);
        } else if (i >= 1){
            // other k-half for the out-GEMM (must COMPLETE before our tag releases writers)
            #pragma unroll
            for (int q = 0; q < 4; ++q){
                int ko = q*32 + quad*8;
                B2[2*q]   = load_sys_b128u(hrow + ko);
                B2[2*q+1] = load_sys_b128u(hrow + ko + 4);
            }
        }
        waitcnt0();
        #pragma unroll
        for (int q = 0; q < 8; ++q) regbar4(A[q]);
        if (kh == 0){ regbar1(HO[0]); regbar1(HO[1]); regbar1(HO[2]); regbar1(HO[3]); }
        else if (i >= 1){
            #pragma unroll
            for (int q = 0; q < 8; ++q) regbar4(B2[q]);
        }

        s16x8 ah[4], al[4];
        #pragma unroll
        for (int q = 0; q < 4; ++q) unpack8(A[2*q], A[2*q+1], ah[q], al[q]);

        #pragma unroll
        for (int q = 0; q < 4; ++q){
            s16x8 H = ah[q], L = al[q];
            accR  = MF(H, wfh[0][q], accR);  accR  = MF(H, wfl[0][q], accR);  accR  = MF(L, wfh[0][q], accR);
            accZ  = MF(H, wfh[1][q], accZ);  accZ  = MF(H, wfl[1][q], accZ);  accZ  = MF(L, wfh[1][q], accZ);
            accNh = MF(H, wfh[2][q], accNh); accNh = MF(H, wfl[2][q], accNh); accNh = MF(L, wfh[2][q], accNh);
        }
        if (i > 0){
            #pragma unroll
            for (int q = 0; q < 4; ++q){
                s16x8 H = ah[q], L = al[q];
                accR  = MF(H, mfh[0][q], accR);  accR  = MF(H, mfl[0][q], accR);  accR  = MF(L, mfh[0][q], accR);
                accZ  = MF(H, mfh[1][q], accZ);  accZ  = MF(H, mfl[1][q], accZ);  accZ  = MF(L, mfh[1][q], accZ);
                accNi = MF(H, mfh[2][q], accNi); accNi = MF(H, mfl[2][q], accNi); accNi = MF(L, mfh[2][q], accNi);
            }
        }

        const int par = g & 1;
        if (kh == 1){
            float* pb = &s_part[m*2 + par][0][0] + lane*4;
            *(f32x4*)(pb)       = accR;
            *(f32x4*)(pb + 256) = accZ;
            *(f32x4*)(pb + 512) = accNi;
            *(f32x4*)(pb + 768) = accNh;
            if (lane == 0)
                __hip_atomic_store(&s_flag[m], g + 1, __ATOMIC_RELEASE, __HIP_MEMORY_SCOPE_WORKGROUP);
            if (i >= 1){
                // out_{i-1} = h^d_i @ regW^T + regb (off the critical path)
                s16x8 bh[4], bl[4];
                #pragma unroll
                for (int q = 0; q < 4; ++q) unpack8(B2[2*q], B2[2*q+1], bh[q], bl[q]);
                float b3 = s_bias[96 + (lcol & 3)];
                f32x4 oa = (f32x4){b3, b3, b3, b3};
                #pragma unroll
                for (int q8 = 0; q8 < 8; ++q8){
                    s16x8 H = (q8 < 4) ? bh[q8] : ah[q8-4];
                    s16x8 L = (q8 < 4) ? bl[q8] : al[q8-4];
                    s16x8 rh = *(const s16x8*)&s_rw[0][q8][lane][0];
                    s16x8 rl = *(const s16x8*)&s_rw[1][q8][lane][0];
                    oa = MF(H, rh, oa); oa = MF(H, rl, oa); oa = MF(L, rh, oa);
                }
                if (lcol < 4){
                    #pragma unroll
                    for (int j = 0; j < 4; ++j)
                        out[(size_t)(bg*32 + m*16 + quad*4 + j)*(TSTEPS*Fsz)
                            + (size_t)(i-1)*Fsz + hb*4 + lcol] = oa[j];
                }
            }
        } else {
            while (__hip_atomic_load(&s_flag[m], __ATOMIC_ACQUIRE, __HIP_MEMORY_SCOPE_WORKGROUP) < g + 1) {}
            const float* pb = &s_part[m*2 + par][0][0] + lane*4;
            accR  += *(const f32x4*)(pb);
            accZ  += *(const f32x4*)(pb + 256);
            accNi += *(const f32x4*)(pb + 512);
            accNh += *(const f32x4*)(pb + 768);
            #pragma unroll
            for (int j = 0; j < 4; ++j){
                float R, Z, N;
                if (i == 0){
                    const float* gp = gi0 + (size_t)(bg*32 + m*16 + quad*4 + j)*G3 + hcol;
                    R = sigmoidf_(accR[j] + gp[0]   + s_bias[64 + lcol]);
                    Z = sigmoidf_(accZ[j] + gp[256] + s_bias[80 + lcol]);
                    N = tanhf(accNi[j] + gp[512] + R*(accNh[j] + s_bias[48 + lcol]));
                } else {
                    R = sigmoidf_(accR[j] + s_bias[lcol]);
                    Z = sigmoidf_(accZ[j] + s_bias[16 + lcol]);
                    N = tanhf(accNi[j] + s_bias[32 + lcol] + R*(accNh[j] + s_bias[48 + lcol]));
                }
                float hold = bf16_to_f((unsigned short)(HO[j] >> 16))
                           + bf16_to_f((unsigned short)(HO[j] & 0xFFFFu));
                float hv = (1.0f - Z)*N + Z*hold;
                unsigned short p1 = bf16_rne(hv);
                unsigned short p0 = bf16_rne(hv - bf16_to_f(p1));
                store_sys_b32u(hout + (size_t)(bg*32 + m*16 + quad*4 + j)*256 + hcol,
                               (((unsigned)p1) << 16) | (unsigned)p0);
            }
            waitcnt0();
            if (lane == 0)
                store_sys_b32u((unsigned*)(tags + bg*32 + hb*2 + m), (unsigned)(g + 1));
        }
    }

    // ---- final out_{127} from h^d_128 (in hbuf parity 0) ----
    if (kh == 1){
        poll_ge(mytags + (lane & 31), 2*TSTEPS);
        const unsigned* hrow = hbuf + (size_t)(bg*32 + m*16 + lcol)*256;
        u32x4 C[16];
        #pragma unroll
        for (int q8 = 0; q8 < 8; ++q8){
            int ko = q8*32 + quad*8;
            C[2*q8]   = load_sys_b128u(hrow + ko);
            C[2*q8+1] = load_sys_b128u(hrow + ko + 4);
        }
        waitcnt0();
        #pragma unroll
        for (int q = 0; q < 16; ++q) regbar4(C[q]);
        float b3 = s_bias[96 + (lcol & 3)];
        f32x4 oa = (f32x4){b3, b3, b3, b3};
        #pragma unroll
        for (int q8 = 0; q8 < 8; ++q8){
            s16x8 H, L; unpack8(C[2*q8], C[2*q8+1], H, L);
            s16x8 rh = *(const s16x8*)&s_rw[0][q8][lane][0];
            s16x8 rl = *(const s16x8*)&s_rw[1][q8][lane][0];
            oa = MF(H, rh, oa); oa = MF(H, rl, oa); oa = MF(L, rh, oa);
        }
        if (lcol < 4){
            #pragma unroll
            for (int j = 0; j < 4; ++j)
                out[(size_t)(bg*32 + m*16 + quad*4 + j)*(TSTEPS*Fsz)
                    + (size_t)(TSTEPS-1)*Fsz + hb*4 + lcol] = oa[j];
        }
    }
}

extern "C" void kernel_launch(void* const* d_in, const int* in_sizes, int n_in,
                              void* d_out, int out_size, void* d_ws, size_t ws_size,
                              hipStream_t stream)
{
    (void)in_sizes; (void)n_in; (void)out_size; (void)ws_size;
    const float* x    = (const float*)d_in[0];
    const float* eWih = (const float*)d_in[1];
    const float* eWhh = (const float*)d_in[2];
    const float* ebih = (const float*)d_in[3];
    const float* ebhh = (const float*)d_in[4];
    const float* dWih = (const float*)d_in[5];
    const float* dWhh = (const float*)d_in[6];
    const float* dbih = (const float*)d_in[7];
    const float* dbhh = (const float*)d_in[8];
    const float* regW = (const float*)d_in[9];
    const float* regb = (const float*)d_in[10];
    float* out = (float*)d_out;

    unsigned* hbuf = (unsigned*)d_ws;                    // 2*512*256 u32 (packed hi/lo bf16)
    float* Mw    = (float*)d_ws + 2*Bsz*Hsz;             // 768*256
    float* gi0   = Mw + G3*Hsz;                          // 512*768
    float* cfold = gi0 + Bsz*G3;                         // 768 (+pad)
    int*   tags  = (int*)(cfold + 1024);                 // 16*32 ints

    hipMemsetAsync(hbuf, 0, (size_t)Bsz*Hsz*sizeof(unsigned), stream); // h^0 = 0
    hipMemsetAsync(tags, 0, (size_t)BG*32*sizeof(int), stream);

    hipLaunchKernelGGL(gru_setup, dim3(2307), dim3(256), 0, stream,
                       x, dWih, dbih, regW, regb, Mw, cfold, gi0);

    void* args[] = { (void*)&x, (void*)&eWih, (void*)&eWhh, (void*)&ebih, (void*)&ebhh,
                     (void*)&dWhh, (void*)&dbhh, (void*)&Mw, (void*)&cfold, (void*)&gi0,
                     (void*)&regW, (void*)&regb, (void*)&hbuf, (void*)&tags, (void*)&out };
    hipError_t rc = hipLaunchCooperativeKernel((const void*)gru_persistent,
                                               dim3(NBLK), dim3(NTHR), args, 0, stream);
    if (rc != hipSuccess) {
        hipLaunchKernelGGL(gru_persistent, dim3(NBLK), dim3(NTHR), 0, stream,
                           x, eWih, eWhh, ebih, ebhh, dWhh, dbhh, Mw, cfold, gi0,
                           regW, regb, hbuf, tags, out);
    }
}

// Round 7
// 1645.406 us; speedup vs baseline: 1.0034x; 1.0034x over previous
//
#include <hip/hip_runtime.h>
#include <math.h>

#define Bsz 512
#define Fsz 64
#define Hsz 256
#define TSTEPS 128
#define G3 768

#define BG 16
#define HB 16
#define NBLK 256
#define NTHR 256
#define PARU32 262144          // u32 per parity buffer
#define DSM_BYTES (48*1024)    // pad: static(~33KB)+dyn(48KB) > 80KB -> 1 block/CU

typedef float f32x4 __attribute__((ext_vector_type(4)));
typedef short s16x8 __attribute__((ext_vector_type(8)));
typedef unsigned int u32x4 __attribute__((ext_vector_type(4)));
typedef unsigned int u32x2 __attribute__((ext_vector_type(2)));

#define MF(a,b,c) __builtin_amdgcn_mfma_f32_16x16x32_bf16(a,b,c,0,0,0)

static __device__ __forceinline__ unsigned short bf16_rne(float f){
    union { float f; unsigned u; } v; v.f = f;
    return (unsigned short)((v.u + 0x7FFFu + ((v.u >> 16) & 1u)) >> 16);
}
static __device__ __forceinline__ float bf16_to_f(unsigned short h){
    union { unsigned u; float f; } v; v.u = ((unsigned)h) << 16; return v.f;
}
static __device__ __forceinline__ void split8(const float* p, s16x8& hi, s16x8& lo){
    union { s16x8 v; unsigned short e[8]; } H, L;
    #pragma unroll
    for (int t = 0; t < 8; ++t){
        float f = p[t];
        unsigned short h = bf16_rne(f);
        H.e[t] = h; L.e[t] = bf16_rne(f - bf16_to_f(h));
    }
    hi = H.v; lo = L.v;
}
static __device__ __forceinline__ void split8f(f32x4 a, f32x4 b, s16x8& hi, s16x8& lo){
    union { s16x8 v; unsigned short e[8]; } H, L;
    float fv[8] = {a[0],a[1],a[2],a[3],b[0],b[1],b[2],b[3]};
    #pragma unroll
    for (int t = 0; t < 8; ++t){
        unsigned short h = bf16_rne(fv[t]);
        H.e[t] = h; L.e[t] = bf16_rne(fv[t] - bf16_to_f(h));
    }
    hi = H.v; lo = L.v;
}
// 4 self-validating dwordx4 regs (data,tag,data,tag) -> hi/lo bf16 fragments
static __device__ __forceinline__ void unpack_frag(const u32x4* P, s16x8& hi, s16x8& lo){
    union { s16x8 v; unsigned u[4]; } H, L;
    unsigned w[8] = {P[0][0],P[0][2],P[1][0],P[1][2],P[2][0],P[2][2],P[3][0],P[3][2]};
    #pragma unroll
    for (int d = 0; d < 4; ++d){
        unsigned w0 = w[2*d], w1 = w[2*d+1];
        H.u[d] = (w0 >> 16) | (w1 & 0xFFFF0000u);
        L.u[d] = (w0 & 0xFFFFu) | (w1 << 16);
    }
    hi = H.v; lo = L.v;
}
static __device__ __forceinline__ float sigmoidf_(float v){ return 1.0f/(1.0f + expf(-v)); }

// ---- MALL-coherent (cache-bypass) ops: sc0 sc1 = skip L1+L2, device-coherent ----
__device__ __forceinline__ u32x4 load_sys_b128(const unsigned* p){
    u32x4 r; asm volatile("global_load_dwordx4 %0, %1, off sc0 sc1" : "=v"(r) : "v"(p) : "memory"); return r;
}
__device__ __forceinline__ u32x2 load_sys_b64(const unsigned* p){
    u32x2 r; asm volatile("global_load_dwordx2 %0, %1, off sc0 sc1" : "=v"(r) : "v"(p) : "memory"); return r;
}
__device__ __forceinline__ void store_sys_b64(unsigned* p, u32x2 v){
    asm volatile("global_store_dwordx2 %0, %1, off sc0 sc1" :: "v"(p), "v"(v) : "memory");
}
__device__ __forceinline__ void waitcnt0(){ asm volatile("s_waitcnt vmcnt(0)" ::: "memory"); }
__device__ __forceinline__ void regbar4(u32x4& v){ asm volatile("" : "+v"(v)); }
__device__ __forceinline__ void regbar2(u32x2& v){ asm volatile("" : "+v"(v)); }

// cheap probe: 1 dwordx4 per lane (2 tags), throttled; full validate comes after
__device__ __forceinline__ void probe_wait(const unsigned* pa, unsigned gexp){
    int ready;
    do {
        u32x4 pr;
        asm volatile("global_load_dwordx4 %0, %1, off sc0 sc1\n\ts_waitcnt vmcnt(0)"
                     : "=v"(pr) : "v"(pa) : "memory");
        ready = __all((pr[1] == gexp) & (pr[3] == gexp));
        if (!ready) __builtin_amdgcn_s_sleep(1);
    } while (!ready);
}

// ---------------- setup: M = dec_Wih@reg_W, cfold = dec_Wih@reg_b + dec_bih,
// ---------------- gi0 = x[:,127,:]@dec_Wih.T + dec_bih
extern "C" __global__ void gru_setup(const float* __restrict__ x,
                                     const float* __restrict__ dWih,
                                     const float* __restrict__ dbih,
                                     const float* __restrict__ regW,
                                     const float* __restrict__ regb,
                                     float* __restrict__ Mw,
                                     float* __restrict__ cfold,
                                     float* __restrict__ gi0)
{
    int idx = blockIdx.x*blockDim.x + threadIdx.x;
    if (idx < G3*Hsz) {
        int g = idx >> 8, j = idx & 255;
        float a = 0.f;
        #pragma unroll 8
        for (int f = 0; f < Fsz; ++f) a += dWih[g*Fsz + f]*regW[f*Hsz + j];
        Mw[idx] = a;
    } else if (idx < G3*Hsz + G3) {
        int g = idx - G3*Hsz;
        float a = dbih[g];
        #pragma unroll 8
        for (int f = 0; f < Fsz; ++f) a += dWih[g*Fsz + f]*regb[f];
        cfold[g] = a;
    } else {
        int e = idx - (G3*Hsz + G3);
        if (e < Bsz*G3) {
            int b = e / G3, g = e - b*G3;
            const float* xp = x + (size_t)b*(256*64) + 127*64;
            float a = dbih[g];
            #pragma unroll 8
            for (int f = 0; f < Fsz; ++f) a += xp[f]*dWih[g*Fsz + f];
            gi0[e] = a;
        }
    }
}

// ---------------- persistent GRU kernel (tag-in-data, MALL exchange) ----------------
extern "C" __global__ void __launch_bounds__(NTHR, 1)
gru_persistent(const float* __restrict__ x,
               const float* __restrict__ eWih, const float* __restrict__ eWhh,
               const float* __restrict__ ebih, const float* __restrict__ ebhh,
               const float* __restrict__ dWhh, const float* __restrict__ dbhh,
               const float* __restrict__ Mw,   const float* __restrict__ cfold,
               const float* __restrict__ gi0,  const float* __restrict__ regW,
               const float* __restrict__ regb,
               unsigned* __restrict__ hbuf,
               float* __restrict__ out)
{
    extern __shared__ char dyn_pad[];          // occupancy pad only
    __shared__ float s_part[4][4][256];
    __shared__ float s_bias[128];
    __shared__ unsigned short s_rw[2][8][64][8];
    __shared__ int s_flag[2];
    (void)dyn_pad;

    const int tid  = threadIdx.x;
    const int wv   = tid >> 6;
    const int m    = wv & 1;       // batch half
    const int kh   = wv >> 1;      // k half
    const int lane = tid & 63;
    const int quad = lane >> 4;
    const int lcol = lane & 15;
    const int bg   = blockIdx.x >> 4;
    const int hb   = blockIdx.x & 15;
    const int hcol = hb*16 + lcol;
    const f32x4 z4 = {0.f,0.f,0.f,0.f};

    // fragment-layout bases (u32-pair element indices)
    const int regA = ((bg*2 + kh)*2 + m)*2048;            // own k-half region
    const int regB = ((bg*2 + 0 )*2 + m)*2048;            // k-low region (out-GEMM)
    const int kh_e = hcol >> 7, k2 = hcol & 127;
    const int cb_col = ((bg*2 + kh_e)*2 + m)*2048
                     + (k2 >> 5)*512 + ((k2 >> 3) & 3)*128 + (k2 & 7);

    if (tid == 0){ s_flag[0] = 0; s_flag[1] = 0; }

    // ---- encoder weight fragments (registers, static over 128 steps) ----
    s16x8 wfh[3][4], wfl[3][4];
    s16x8 ufh[3], ufl[3];
    #pragma unroll
    for (int g3 = 0; g3 < 3; ++g3){
        #pragma unroll
        for (int q = 0; q < 4; ++q)
            split8(eWhh + (size_t)(g3*256 + hcol)*256 + kh*128 + q*32 + quad*8,
                   wfh[g3][q], wfl[g3][q]);
        split8(eWih + (size_t)(g3*256 + hcol)*64 + kh*32 + quad*8, ufh[g3], ufl[g3]);
    }
    if (tid < 16){
        int c = hb*16 + tid;
        s_bias[tid]    = ebih[c]     + ebhh[c];
        s_bias[16+tid] = ebih[256+c] + ebhh[256+c];
        s_bias[32+tid] = ebih[512+c];
        s_bias[48+tid] = ebhh[512+c];
    }
    __syncthreads();

    // =================== ENCODER (g = 0..127) ===================
    for (int g = 0; g < TSTEPS; ++g){
        const unsigned gexp = (unsigned)g;
        const unsigned par  = (unsigned)(g & 1)*PARU32;
        const unsigned par2 = (unsigned)((g + 1) & 1)*PARU32;

        f32x4 accR = z4, accZ = z4, accNi = z4, accNh = z4;

        // x-GEMM (independent of h)
        {
            const float* xp = x + (size_t)(bg*32 + m*16 + lcol)*(256*64)
                              + (size_t)g*64 + kh*32 + quad*8;
            f32x4 xa = *(const f32x4*)xp;
            f32x4 xb = *(const f32x4*)(xp + 4);
            s16x8 xh, xl; split8f(xa, xb, xh, xl);
            accR  = MF(xh, ufh[0], accR);  accR  = MF(xh, ufl[0], accR);  accR  = MF(xl, ufh[0], accR);
            accZ  = MF(xh, ufh[1], accZ);  accZ  = MF(xh, ufl[1], accZ);  accZ  = MF(xl, ufh[1], accZ);
            accNi = MF(xh, ufh[2], accNi); accNi = MF(xh, ufl[2], accNi); accNi = MF(xl, ufh[2], accNi);
        }

        u32x2 ho[4];
        if (g > 0){
            probe_wait(hbuf + par + (unsigned)(regA + 3*512 + quad*128 + lcol*8 + 6)*2u, gexp);
            u32x4 P[16];
            int ok;
            do {
                #pragma unroll
                for (int q = 0; q < 4; ++q)
                    #pragma unroll
                    for (int c = 0; c < 4; ++c)
                        P[q*4+c] = load_sys_b128(hbuf + par +
                            (unsigned)(regA + q*512 + quad*128 + lcol*8 + c*2)*2u);
                if (kh == 0){
                    #pragma unroll
                    for (int j = 0; j < 4; ++j)
                        ho[j] = load_sys_b64(hbuf + par +
                            (unsigned)(cb_col + (quad*4 + j)*8)*2u);
                }
                waitcnt0();
                #pragma unroll
                for (int q = 0; q < 16; ++q) regbar4(P[q]);
                int lok = 1;
                #pragma unroll
                for (int q = 0; q < 16; ++q)
                    lok &= (P[q][1] == gexp) & (P[q][3] == gexp);
                if (kh == 0){
                    #pragma unroll
                    for (int j = 0; j < 4; ++j){ regbar2(ho[j]); lok &= (ho[j][1] == gexp); }
                }
                ok = __all(lok);
            } while (!ok);

            s16x8 ah, al;
            #pragma unroll
            for (int q = 0; q < 4; ++q){
                unpack_frag(&P[q*4], ah, al);
                accR  = MF(ah, wfh[0][q], accR);  accR  = MF(ah, wfl[0][q], accR);  accR  = MF(al, wfh[0][q], accR);
                accZ  = MF(ah, wfh[1][q], accZ);  accZ  = MF(ah, wfl[1][q], accZ);  accZ  = MF(al, wfh[1][q], accZ);
                accNh = MF(ah, wfh[2][q], accNh); accNh = MF(ah, wfl[2][q], accNh); accNh = MF(al, wfh[2][q], accNh);
            }
        }

        const int pslot = m*2 + (g & 1);
        if (kh == 1){
            float* pb = &s_part[pslot][0][0] + lane*4;
            *(f32x4*)(pb)       = accR;
            *(f32x4*)(pb + 256) = accZ;
            *(f32x4*)(pb + 512) = accNi;
            *(f32x4*)(pb + 768) = accNh;
            if (lane == 0)
                __hip_atomic_store(&s_flag[m], g + 1, __ATOMIC_RELEASE, __HIP_MEMORY_SCOPE_WORKGROUP);
        } else {
            while (__hip_atomic_load(&s_flag[m], __ATOMIC_ACQUIRE, __HIP_MEMORY_SCOPE_WORKGROUP) < g + 1) {}
            const float* pb = &s_part[pslot][0][0] + lane*4;
            accR  += *(const f32x4*)(pb);
            accZ  += *(const f32x4*)(pb + 256);
            accNi += *(const f32x4*)(pb + 512);
            accNh += *(const f32x4*)(pb + 768);
            #pragma unroll
            for (int j = 0; j < 4; ++j){
                float R = sigmoidf_(accR[j] + s_bias[lcol]);
                float Z = sigmoidf_(accZ[j] + s_bias[16 + lcol]);
                float N = tanhf(accNi[j] + s_bias[32 + lcol] + R*(accNh[j] + s_bias[48 + lcol]));
                float hold = (g == 0) ? 0.f
                           : bf16_to_f((unsigned short)(ho[j][0] >> 16))
                           + bf16_to_f((unsigned short)(ho[j][0] & 0xFFFFu));
                float hv = (1.0f - Z)*N + Z*hold;
                unsigned short p1 = bf16_rne(hv);
                unsigned short p0 = bf16_rne(hv - bf16_to_f(p1));
                u32x2 pk = { (((unsigned)p1) << 16) | (unsigned)p0, (unsigned)(g + 1) };
                store_sys_b64(hbuf + par2 + (unsigned)(cb_col + (quad*4 + j)*8)*2u, pk);
            }
            // no store-ack needed: tagged data IS the signal
        }
    }

    // ---- decoder weight fragments + biases ----
    __syncthreads();
    s16x8 mfh[3][4], mfl[3][4];
    #pragma unroll
    for (int g3 = 0; g3 < 3; ++g3)
        #pragma unroll
        for (int q = 0; q < 4; ++q){
            split8(dWhh + (size_t)(g3*256 + hcol)*256 + kh*128 + q*32 + quad*8,
                   wfh[g3][q], wfl[g3][q]);
            split8(Mw   + (size_t)(g3*256 + hcol)*256 + kh*128 + q*32 + quad*8,
                   mfh[g3][q], mfl[g3][q]);
        }
    if (wv == 2){
        #pragma unroll
        for (int q8 = 0; q8 < 8; ++q8){
            s16x8 rh, rl;
            split8(regW + (size_t)(hb*4 + (lcol & 3))*256 + q8*32 + quad*8, rh, rl);
            *(s16x8*)&s_rw[0][q8][lane][0] = rh;
            *(s16x8*)&s_rw[1][q8][lane][0] = rl;
        }
    }
    if (tid < 16){
        int c = hb*16 + tid;
        s_bias[tid]      = cfold[c]       + dbhh[c];
        s_bias[16+tid]   = cfold[256+c]   + dbhh[256+c];
        s_bias[32+tid]   = cfold[512+c];
        s_bias[48+tid]   = dbhh[512+c];
        s_bias[64+tid]   = dbhh[c];
        s_bias[80+tid]   = dbhh[256+c];
    }
    if (tid < 4) s_bias[96 + tid] = regb[hb*4 + tid];
    __syncthreads();

    // =================== DECODER (g = 128..255) ===================
    for (int i = 0; i < TSTEPS; ++i){
        const int g = TSTEPS + i;
        const unsigned gexp = (unsigned)g;
        const unsigned par  = (unsigned)(g & 1)*PARU32;
        const unsigned par2 = (unsigned)((g + 1) & 1)*PARU32;

        f32x4 accR = z4, accZ = z4, accNi = z4, accNh = z4;

        probe_wait(hbuf + par + (unsigned)(regA + 3*512 + quad*128 + lcol*8 + 6)*2u, gexp);

        u32x2 ho[4];
        s16x8 ah[4], al[4];
        {
            u32x4 P[16];
            int ok;
            do {
                #pragma unroll
                for (int q = 0; q < 4; ++q)
                    #pragma unroll
                    for (int c = 0; c < 4; ++c)
                        P[q*4+c] = load_sys_b128(hbuf + par +
                            (unsigned)(regA + q*512 + quad*128 + lcol*8 + c*2)*2u);
                if (kh == 0){
                    #pragma unroll
                    for (int j = 0; j < 4; ++j)
                        ho[j] = load_sys_b64(hbuf + par +
                            (unsigned)(cb_col + (quad*4 + j)*8)*2u);
                }
                waitcnt0();
                #pragma unroll
                for (int q = 0; q < 16; ++q) regbar4(P[q]);
                int lok = 1;
                #pragma unroll
                for (int q = 0; q < 16; ++q)
                    lok &= (P[q][1] == gexp) & (P[q][3] == gexp);
                if (kh == 0){
                    #pragma unroll
                    for (int j = 0; j < 4; ++j){ regbar2(ho[j]); lok &= (ho[j][1] == gexp); }
                }
                ok = __all(lok);
            } while (!ok);
            #pragma unroll
            for (int q = 0; q < 4; ++q) unpack_frag(&P[q*4], ah[q], al[q]);
        }

        #pragma unroll
        for (int q = 0; q < 4; ++q){
            s16x8 H = ah[q], L = al[q];
            accR  = MF(H, wfh[0][q], accR);  accR  = MF(H, wfl[0][q], accR);  accR  = MF(L, wfh[0][q], accR);
            accZ  = MF(H, wfh[1][q], accZ);  accZ  = MF(H, wfl[1][q], accZ);  accZ  = MF(L, wfh[1][q], accZ);
            accNh = MF(H, wfh[2][q], accNh); accNh = MF(H, wfl[2][q], accNh); accNh = MF(L, wfh[2][q], accNh);
        }
        if (i > 0){
            #pragma unroll
            for (int q = 0; q < 4; ++q){
                s16x8 H = ah[q], L = al[q];
                accR  = MF(H, mfh[0][q], accR);  accR  = MF(H, mfl[0][q], accR);  accR  = MF(L, mfh[0][q], accR);
                accZ  = MF(H, mfh[1][q], accZ);  accZ  = MF(H, mfl[1][q], accZ);  accZ  = MF(L, mfh[1][q], accZ);
                accNi = MF(H, mfh[2][q], accNi); accNi = MF(H, mfl[2][q], accNi); accNi = MF(L, mfh[2][q], accNi);
            }
        }

        const int pslot = m*2 + (g & 1);
        if (kh == 1){
            float* pb = &s_part[pslot][0][0] + lane*4;
            *(f32x4*)(pb)       = accR;
            *(f32x4*)(pb + 256) = accZ;
            *(f32x4*)(pb + 512) = accNi;
            *(f32x4*)(pb + 768) = accNh;
            if (lane == 0)
                __hip_atomic_store(&s_flag[m], g + 1, __ATOMIC_RELEASE, __HIP_MEMORY_SCOPE_WORKGROUP);
            if (i >= 1){
                // ---- out_{i-1}: load+validate k-low half AFTER the handoff (off critical path) ----
                u32x4 P2[16];
                int ok2;
                do {
                    #pragma unroll
                    for (int q = 0; q < 4; ++q)
                        #pragma unroll
                        for (int c = 0; c < 4; ++c)
                            P2[q*4+c] = load_sys_b128(hbuf + par +
                                (unsigned)(regB + q*512 + quad*128 + lcol*8 + c*2)*2u);
                    waitcnt0();
                    int lok = 1;
                    #pragma unroll
                    for (int q = 0; q < 16; ++q){
                        regbar4(P2[q]);
                        lok &= (P2[q][1] == gexp) & (P2[q][3] == gexp);
                    }
                    ok2 = __all(lok);
                } while (!ok2);

                float b3 = s_bias[96 + (lcol & 3)];
                f32x4 oa = (f32x4){b3, b3, b3, b3};
                #pragma unroll
                for (int q8 = 0; q8 < 8; ++q8){
                    s16x8 H, L;
                    if (q8 < 4) unpack_frag(&P2[q8*4], H, L);
                    else { H = ah[q8-4]; L = al[q8-4]; }
                    s16x8 rh = *(const s16x8*)&s_rw[0][q8][lane][0];
                    s16x8 rl = *(const s16x8*)&s_rw[1][q8][lane][0];
                    oa = MF(H, rh, oa); oa = MF(H, rl, oa); oa = MF(L, rh, oa);
                }
                if (lcol < 4){
                    #pragma unroll
                    for (int j = 0; j < 4; ++j)
                        out[(size_t)(bg*32 + m*16 + quad*4 + j)*(TSTEPS*Fsz)
                            + (size_t)(i-1)*Fsz + hb*4 + lcol] = oa[j];
                }
            }
        } else {
            while (__hip_atomic_load(&s_flag[m], __ATOMIC_ACQUIRE, __HIP_MEMORY_SCOPE_WORKGROUP) < g + 1) {}
            const float* pb = &s_part[pslot][0][0] + lane*4;
            accR  += *(const f32x4*)(pb);
            accZ  += *(const f32x4*)(pb + 256);
            accNi += *(const f32x4*)(pb + 512);
            accNh += *(const f32x4*)(pb + 768);
            #pragma unroll
            for (int j = 0; j < 4; ++j){
                float R, Z, N;
                if (i == 0){
                    const float* gp = gi0 + (size_t)(bg*32 + m*16 + quad*4 + j)*G3 + hcol;
                    R = sigmoidf_(accR[j] + gp[0]   + s_bias[64 + lcol]);
                    Z = sigmoidf_(accZ[j] + gp[256] + s_bias[80 + lcol]);
                    N = tanhf(accNi[j] + gp[512] + R*(accNh[j] + s_bias[48 + lcol]));
                } else {
                    R = sigmoidf_(accR[j] + s_bias[lcol]);
                    Z = sigmoidf_(accZ[j] + s_bias[16 + lcol]);
                    N = tanhf(accNi[j] + s_bias[32 + lcol] + R*(accNh[j] + s_bias[48 + lcol]));
                }
                float hold = bf16_to_f((unsigned short)(ho[j][0] >> 16))
                           + bf16_to_f((unsigned short)(ho[j][0] & 0xFFFFu));
                float hv = (1.0f - Z)*N + Z*hold;
                unsigned short p1 = bf16_rne(hv);
                unsigned short p0 = bf16_rne(hv - bf16_to_f(p1));
                u32x2 pk = { (((unsigned)p1) << 16) | (unsigned)p0, (unsigned)(g + 1) };
                store_sys_b64(hbuf + par2 + (unsigned)(cb_col + (quad*4 + j)*8)*2u, pk);
            }
        }
    }

    // ---- final out_{127} from h_256 (parity 0, tag 256) ----
    if (kh == 1){
        const unsigned gexp = 2*TSTEPS;
        probe_wait(hbuf + (unsigned)(regA + 3*512 + quad*128 + lcol*8 + 6)*2u, gexp);
        u32x4 P[16], P2[16];
        int ok;
        do {
            #pragma unroll
            for (int q = 0; q < 4; ++q)
                #pragma unroll
                for (int c = 0; c < 4; ++c){
                    P[q*4+c]  = load_sys_b128(hbuf +
                        (unsigned)(regA + q*512 + quad*128 + lcol*8 + c*2)*2u);
                    P2[q*4+c] = load_sys_b128(hbuf +
                        (unsigned)(regB + q*512 + quad*128 + lcol*8 + c*2)*2u);
                }
            waitcnt0();
            int lok = 1;
            #pragma unroll
            for (int q = 0; q < 16; ++q){
                regbar4(P[q]); regbar4(P2[q]);
                lok &= (P[q][1] == gexp) & (P[q][3] == gexp);
                lok &= (P2[q][1] == gexp) & (P2[q][3] == gexp);
            }
            ok = __all(lok);
        } while (!ok);

        float b3 = s_bias[96 + (lcol & 3)];
        f32x4 oa = (f32x4){b3, b3, b3, b3};
        #pragma unroll
        for (int q8 = 0; q8 < 8; ++q8){
            s16x8 H, L;
            if (q8 < 4) unpack_frag(&P2[q8*4], H, L);
            else        unpack_frag(&P[(q8-4)*4], H, L);
            s16x8 rh = *(const s16x8*)&s_rw[0][q8][lane][0];
            s16x8 rl = *(const s16x8*)&s_rw[1][q8][lane][0];
            oa = MF(H, rh, oa); oa = MF(H, rl, oa); oa = MF(L, rh, oa);
        }
        if (lcol < 4){
            #pragma unroll
            for (int j = 0; j < 4; ++j)
                out[(size_t)(bg*32 + m*16 + quad*4 + j)*(TSTEPS*Fsz)
                    + (size_t)(TSTEPS-1)*Fsz + hb*4 + lcol] = oa[j];
        }
    }
}

extern "C" void kernel_launch(void* const* d_in, const int* in_sizes, int n_in,
                              void* d_out, int out_size, void* d_ws, size_t ws_size,
                              hipStream_t stream)
{
    (void)in_sizes; (void)n_in; (void)out_size; (void)ws_size;
    const float* x    = (const float*)d_in[0];
    const float* eWih = (const float*)d_in[1];
    const float* eWhh = (const float*)d_in[2];
    const float* ebih = (const float*)d_in[3];
    const float* ebhh = (const float*)d_in[4];
    const float* dWih = (const float*)d_in[5];
    const float* dWhh = (const float*)d_in[6];
    const float* dbih = (const float*)d_in[7];
    const float* dbhh = (const float*)d_in[8];
    const float* regW = (const float*)d_in[9];
    const float* regb = (const float*)d_in[10];
    float* out = (float*)d_out;

    char* base = (char*)d_ws;
    unsigned* hbuf = (unsigned*)base;                    // 2 * 262144 u32 = 2 MB
    float* Mw    = (float*)(base + 2u*PARU32*4u);        // 768*256
    float* gi0   = Mw + G3*Hsz;                          // 512*768
    float* cfold = gi0 + Bsz*G3;                         // 768 (+pad)

    hipLaunchKernelGGL(gru_setup, dim3(2307), dim3(256), 0, stream,
                       x, dWih, dbih, regW, regb, Mw, cfold, gi0);

    hipFuncSetAttribute((const void*)gru_persistent,
                        hipFuncAttributeMaxDynamicSharedMemorySize, DSM_BYTES);

    void* args[] = { (void*)&x, (void*)&eWih, (void*)&eWhh, (void*)&ebih, (void*)&ebhh,
                     (void*)&dWhh, (void*)&dbhh, (void*)&Mw, (void*)&cfold, (void*)&gi0,
                     (void*)&regW, (void*)&regb, (void*)&hbuf, (void*)&out };
    hipError_t rc = hipLaunchCooperativeKernel((const void*)gru_persistent,
                                               dim3(NBLK), dim3(NTHR), args,
                                               DSM_BYTES, stream);
    if (rc != hipSuccess) {
        hipLaunchKernelGGL(gru_persistent, dim3(NBLK), dim3(NTHR), DSM_BYTES, stream,
                           x, eWih, eWhh, ebih, ebhh, dWhh, dbhh, Mw, cfold, gi0,
                           regW, regb, hbuf, out);
    }
}

// Round 8
// 1566.259 us; speedup vs baseline: 1.0541x; 1.0505x over previous
//
#include <hip/hip_runtime.h>
#include <math.h>

#define Bsz 512
#define Fsz 64
#define Hsz 256
#define TSTEPS 128
#define G3 768

#define NBLK 256
#define NTHR 256
// h layout: per parity, 512 rows x 96 granules x 16B. granule = {c0,c1,c2,tag}
#define ROWG 96
#define PARU32 (512*ROWG*4)          // 196608 u32 per parity
#define SMEM_BYTES (49152 + 65536 + 512)   // htile + partials(2-parity) + bias  (~112.5KB -> 1 blk/CU)

typedef float f32x4 __attribute__((ext_vector_type(4)));
typedef short s16x8 __attribute__((ext_vector_type(8)));
typedef unsigned int u32x4 __attribute__((ext_vector_type(4)));

#define MF(a,b,c) __builtin_amdgcn_mfma_f32_16x16x32_bf16(a,b,c,0,0,0)
// split-bf16 triple product: acc += A*B with A=ah+al, B=bh+bl (drop al*bl)
#define TRIP(acc, ah, al, bh, bl) { acc = MF(ah,bh,acc); acc = MF(ah,bl,acc); acc = MF(al,bh,acc); }

static __device__ __forceinline__ unsigned short bf16_rne(float f){
    union { float f; unsigned u; } v; v.f = f;
    return (unsigned short)((v.u + 0x7FFFu + ((v.u >> 16) & 1u)) >> 16);
}
static __device__ __forceinline__ float bf16_to_f(unsigned short h){
    union { unsigned u; float f; } v; v.u = ((unsigned)h) << 16; return v.f;
}
static __device__ __forceinline__ void split8(const float* p, s16x8& hi, s16x8& lo){
    union { s16x8 v; unsigned short e[8]; } H, L;
    #pragma unroll
    for (int t = 0; t < 8; ++t){
        float f = p[t];
        unsigned short h = bf16_rne(f);
        H.e[t] = h; L.e[t] = bf16_rne(f - bf16_to_f(h));
    }
    hi = H.v; lo = L.v;
}
static __device__ __forceinline__ void split8f(f32x4 a, f32x4 b, s16x8& hi, s16x8& lo){
    union { s16x8 v; unsigned short e[8]; } H, L;
    float fv[8] = {a[0],a[1],a[2],a[3],b[0],b[1],b[2],b[3]};
    #pragma unroll
    for (int t = 0; t < 8; ++t){
        unsigned short h = bf16_rne(fv[t]);
        H.e[t] = h; L.e[t] = bf16_rne(fv[t] - bf16_to_f(h));
    }
    hi = H.v; lo = L.v;
}
static __device__ __forceinline__ void pack_hilo(const unsigned* d, s16x8& hi, s16x8& lo){
    union { s16x8 v; unsigned u[4]; } H, L;
    #pragma unroll
    for (int k = 0; k < 4; ++k){
        unsigned w0 = d[2*k], w1 = d[2*k+1];
        H.u[k] = (w0 >> 16) | (w1 & 0xFFFF0000u);
        L.u[k] = (w0 & 0xFFFFu) | (w1 << 16);
    }
    hi = H.v; lo = L.v;
}
// A-frag (8 cols) from 4 LDS granules starting at granule index gidx; qp = quad&1
static __device__ __forceinline__ void frag_lds(const unsigned* sh, int gidx, int qp,
                                                s16x8& hi, s16x8& lo){
    const u32x4* p = (const u32x4*)(sh + gidx*4);
    u32x4 g0 = p[0], g1 = p[1], g2 = p[2], g3 = p[3];
    unsigned d[8];
    if (qp){ d[0]=g0[2];d[1]=g1[0];d[2]=g1[1];d[3]=g1[2];d[4]=g2[0];d[5]=g2[1];d[6]=g2[2];d[7]=g3[0]; }
    else   { d[0]=g0[0];d[1]=g0[1];d[2]=g0[2];d[3]=g1[0];d[4]=g1[1];d[5]=g1[2];d[6]=g2[0];d[7]=g2[1]; }
    pack_hilo(d, hi, lo);
}
static __device__ __forceinline__ float sigmoidf_(float v){ return 1.0f/(1.0f + expf(-v)); }

// ---- MALL-coherent cache-bypass ops ----
__device__ __forceinline__ u32x4 load_sys_b128(const unsigned* p){
    u32x4 r; asm volatile("global_load_dwordx4 %0, %1, off sc0 sc1" : "=v"(r) : "v"(p) : "memory"); return r;
}
__device__ __forceinline__ void store_sys_b128(unsigned* p, u32x4 v){
    asm volatile("global_store_dwordx4 %0, %1, off sc0 sc1" :: "v"(p), "v"(v) : "memory");
}
__device__ __forceinline__ void waitcnt0(){ asm volatile("s_waitcnt vmcnt(0)" ::: "memory"); }
__device__ __forceinline__ void regbar4(u32x4& v){ asm volatile("" : "+v"(v)); }

// cheap 2-granule probe until both tags == g (all lanes)
__device__ __forceinline__ void probe_wait(const unsigned* a0, const unsigned* a1, unsigned g){
    int ready;
    do {
        u32x4 p0, p1;
        asm volatile("global_load_dwordx4 %0, %2, off sc0 sc1\n\t"
                     "global_load_dwordx4 %1, %3, off sc0 sc1\n\t"
                     "s_waitcnt vmcnt(0)"
                     : "=v"(p0), "=v"(p1) : "v"(a0), "v"(a1) : "memory");
        ready = __all((p0[3] == g) & (p1[3] == g));
        if (!ready) __builtin_amdgcn_s_sleep(1);
    } while (!ready);
}

// ---------------- setup (unchanged) ----------------
extern "C" __global__ void gru_setup(const float* __restrict__ x,
                                     const float* __restrict__ dWih,
                                     const float* __restrict__ dbih,
                                     const float* __restrict__ regW,
                                     const float* __restrict__ regb,
                                     float* __restrict__ Mw,
                                     float* __restrict__ cfold,
                                     float* __restrict__ gi0)
{
    int idx = blockIdx.x*blockDim.x + threadIdx.x;
    if (idx < G3*Hsz) {
        int g = idx >> 8, j = idx & 255;
        float a = 0.f;
        #pragma unroll 8
        for (int f = 0; f < Fsz; ++f) a += dWih[g*Fsz + f]*regW[f*Hsz + j];
        Mw[idx] = a;
    } else if (idx < G3*Hsz + G3) {
        int g = idx - G3*Hsz;
        float a = dbih[g];
        #pragma unroll 8
        for (int f = 0; f < Fsz; ++f) a += dWih[g*Fsz + f]*regb[f];
        cfold[g] = a;
    } else {
        int e = idx - (G3*Hsz + G3);
        if (e < Bsz*G3) {
            int b = e / G3, g = e - b*G3;
            const float* xp = x + (size_t)b*(256*64) + 127*64;
            float a = dbih[g];
            #pragma unroll 8
            for (int f = 0; f < Fsz; ++f) a += xp[f]*dWih[g*Fsz + f];
            gi0[e] = a;
        }
    }
}

// ---------------- persistent GRU (dense tag-in-data exchange) ----------------
extern "C" __global__ void __launch_bounds__(NTHR, 1)
gru_persistent(const float* __restrict__ x,
               const float* __restrict__ eWih, const float* __restrict__ eWhh,
               const float* __restrict__ ebih, const float* __restrict__ ebhh,
               const float* __restrict__ dWhh, const float* __restrict__ dbhh,
               const float* __restrict__ Mw,   const float* __restrict__ cfold,
               const float* __restrict__ gi0,  const float* __restrict__ regW,
               const float* __restrict__ regb,
               unsigned* __restrict__ hbuf,
               float* __restrict__ out)
{
    extern __shared__ unsigned lds_u[];
    unsigned* s_h   = lds_u;                       // 4 regions x 32 rows x 24 granules x 4 u32
    float* s_part   = (float*)(lds_u + 12288);     // [par][wave][m][4 slots][256]
    float* s_bias   = s_part + 16384;              // 128 floats
    __shared__ int s_flag[4], s_done[4];

    const int tid  = threadIdx.x;
    const int wv   = tid >> 6;        // k quarter 0..3
    const int lane = tid & 63;
    const int quad = lane >> 4;
    const int qp   = quad & 1;
    const int lcol = lane & 15;
    const int bg   = blockIdx.x >> 4;
    const int hb   = blockIdx.x & 15;
    const int hcol = hb*16 + lcol;
    const f32x4 z4 = {0.f,0.f,0.f,0.f};

    if (tid < 4){ s_flag[tid] = 0; s_done[tid] = 0; }

    // validate-load address pieces (12 granules per lane, contiguous 384B runs per row)
    int vrow[12], vgr[12];
    #pragma unroll
    for (int i = 0; i < 12; ++i){
        unsigned flat = (unsigned)(i*64 + lane);
        vrow[i] = flat/24u; vgr[i] = flat - (flat/24u)*24u;
    }
    // probe addresses (granule offsets within parity region)
    const unsigned pr0 = (unsigned)(((bg*32 + vrow[0])*ROWG + wv*24 + vgr[0]))*4u;
    const unsigned pr1 = (unsigned)(((bg*32 + vrow[6])*ROWG + wv*24 + vgr[6]))*4u;

    // ---- encoder weights ----
    s16x8 wfh[3][2], wfl[3][2];   // Whh k-quarter: [gate][q], k = wv*64 + q*32 + quad*8
    s16x8 ufh[3], ufl[3];         // Wih (waves 2,3): k = (wv-2)*32 + quad*8
    #pragma unroll
    for (int g3 = 0; g3 < 3; ++g3)
        #pragma unroll
        for (int q = 0; q < 2; ++q)
            split8(eWhh + (size_t)(g3*256 + hcol)*256 + wv*64 + q*32 + quad*8,
                   wfh[g3][q], wfl[g3][q]);
    if (wv >= 2)
        #pragma unroll
        for (int g3 = 0; g3 < 3; ++g3)
            split8(eWih + (size_t)(g3*256 + hcol)*64 + (wv-2)*32 + quad*8, ufh[g3], ufl[g3]);
    if (tid < 16){
        int c = hb*16 + tid;
        s_bias[tid]    = ebih[c]     + ebhh[c];
        s_bias[16+tid] = ebih[256+c] + ebhh[256+c];
        s_bias[32+tid] = ebih[512+c];
        s_bias[48+tid] = ebhh[512+c];
    }
    float hold[4] = {0.f,0.f,0.f,0.f};   // h_old registers (epilogue waves, rows quad*4+j)
    __syncthreads();

    // =================== ENCODER (g = 0..127) ===================
    for (int g = 0; g < TSTEPS; ++g){
        const unsigned gexp = (unsigned)g;
        const unsigned parb  = (unsigned)(g & 1)*PARU32;
        const unsigned parb2 = (unsigned)((g + 1) & 1)*PARU32;
        const int par = g & 1;

        f32x4 aR[2]={z4,z4}, aZ[2]={z4,z4}, aNi[2]={z4,z4}, aNh[2]={z4,z4};

        // x partials (waves 2,3), independent of h
        if (wv >= 2){
            #pragma unroll
            for (int m = 0; m < 2; ++m){
                const float* xp = x + (size_t)(bg*32 + m*16 + lcol)*(256*64)
                                  + (size_t)g*64 + (wv-2)*32 + quad*8;
                f32x4 xa = *(const f32x4*)xp, xb = *(const f32x4*)(xp+4);
                s16x8 xh, xl; split8f(xa, xb, xh, xl);
                TRIP(aR[m],  xh, xl, ufh[0], ufl[0]);
                TRIP(aZ[m],  xh, xl, ufh[1], ufl[1]);
                TRIP(aNi[m], xh, xl, ufh[2], ufl[2]);
            }
        }

        if (g > 0){
            probe_wait(hbuf + parb + pr0, hbuf + parb + pr1, gexp);
            u32x4 P[12];
            int ok;
            do {
                #pragma unroll
                for (int i = 0; i < 12; ++i)
                    P[i] = load_sys_b128(hbuf + parb +
                        (unsigned)((bg*32 + vrow[i])*ROWG + wv*24 + vgr[i])*4u);
                waitcnt0();
                int lok = 1;
                #pragma unroll
                for (int i = 0; i < 12; ++i){ regbar4(P[i]); lok &= (P[i][3] == gexp); }
                ok = __all(lok);
                if (!ok) __builtin_amdgcn_s_sleep(1);
            } while (!ok);
            // stage to LDS (own region)
            #pragma unroll
            for (int i = 0; i < 12; ++i)
                *(u32x4*)(s_h + ((wv*32 + vrow[i])*24 + vgr[i])*4) = P[i];
            // h-MFMA (own k quarter)
            #pragma unroll
            for (int m = 0; m < 2; ++m)
                #pragma unroll
                for (int q = 0; q < 2; ++q){
                    int gidx = (wv*32 + m*16 + lcol)*24 + (q*2 + (quad>>1))*6 + qp*2;
                    s16x8 ah, al; frag_lds(s_h, gidx, qp, ah, al);
                    TRIP(aR[m],  ah, al, wfh[0][q], wfl[0][q]);
                    TRIP(aZ[m],  ah, al, wfh[1][q], wfl[1][q]);
                    TRIP(aNh[m], ah, al, wfh[2][q], wfl[2][q]);
                }
        }

        // publish partials (skip own-m for epilogue waves)
        #pragma unroll
        for (int m = 0; m < 2; ++m){
            if (wv < 2 && wv == m) continue;
            float* pb = s_part + ((par*4 + wv)*2 + m)*1024 + lane*4;
            *(f32x4*)(pb)      = aR[m];  *(f32x4*)(pb+256) = aZ[m];
            *(f32x4*)(pb+512)  = aNi[m]; *(f32x4*)(pb+768) = aNh[m];
        }
        __hip_atomic_store(&s_flag[wv], g + 1, __ATOMIC_RELEASE, __HIP_MEMORY_SCOPE_WORKGROUP);

        if (wv < 2){
            const int m = wv;
            #pragma unroll
            for (int w = 0; w < 4; ++w){
                if (w == wv) continue;
                while (__hip_atomic_load(&s_flag[w], __ATOMIC_ACQUIRE, __HIP_MEMORY_SCOPE_WORKGROUP) < g + 1) {}
            }
            f32x4 R = aR[m], Z = aZ[m], Ni = aNi[m], Nh = aNh[m];
            #pragma unroll
            for (int w = 0; w < 4; ++w){
                if (w == wv) continue;
                const float* pb = s_part + ((par*4 + w)*2 + m)*1024 + lane*4;
                R += *(const f32x4*)(pb);     Z  += *(const f32x4*)(pb+256);
                Ni += *(const f32x4*)(pb+512); Nh += *(const f32x4*)(pb+768);
            }
            unsigned pk[4];
            #pragma unroll
            for (int j = 0; j < 4; ++j){
                float r = sigmoidf_(R[j] + s_bias[lcol]);
                float z = sigmoidf_(Z[j] + s_bias[16+lcol]);
                float n = tanhf(Ni[j] + s_bias[32+lcol] + r*(Nh[j] + s_bias[48+lcol]));
                float hv = (1.0f - z)*n + z*hold[j];
                unsigned short p1 = bf16_rne(hv);
                unsigned short p0 = bf16_rne(hv - bf16_to_f(p1));
                pk[j] = (((unsigned)p1) << 16) | (unsigned)p0;
                hold[j] = bf16_to_f(p1) + bf16_to_f(p0);
            }
            // gather 3 cols per granule via shfl, store {c0,c1,c2,tag}
            #pragma unroll
            for (int j = 0; j < 4; ++j){
                unsigned d0 = __shfl(pk[j], quad*16 + ((3*lcol    ) & 15));
                unsigned d1 = __shfl(pk[j], quad*16 + ((3*lcol + 1) & 15));
                unsigned d2 = __shfl(pk[j], quad*16 + ((3*lcol + 2) & 15));
                if (lcol < 6){
                    u32x4 gr = {d0, d1, d2, (unsigned)(g + 1)};
                    store_sys_b128(hbuf + parb2 +
                        (unsigned)((bg*32 + m*16 + quad*4 + j)*ROWG + hb*6 + lcol)*4u, gr);
                }
            }
        }
    }

    // ---- phase switch: decoder weights ----
    __syncthreads();
    s16x8 mfh[3][2], mfl[3][2];
    #pragma unroll
    for (int g3 = 0; g3 < 3; ++g3)
        #pragma unroll
        for (int q = 0; q < 2; ++q){
            split8(dWhh + (size_t)(g3*256 + hcol)*256 + wv*64 + q*32 + quad*8,
                   wfh[g3][q], wfl[g3][q]);
            split8(Mw   + (size_t)(g3*256 + hcol)*256 + wv*64 + q*32 + quad*8,
                   mfh[g3][q], mfl[g3][q]);
        }
    s16x8 rwh[8], rwl[8];
    if (wv >= 2)
        #pragma unroll
        for (int q8 = 0; q8 < 8; ++q8)
            split8(regW + (size_t)(hb*4 + (lcol & 3))*256 + q8*32 + quad*8, rwh[q8], rwl[q8]);
    if (tid < 16){
        int c = hb*16 + tid;
        s_bias[tid]    = cfold[c]     + dbhh[c];
        s_bias[16+tid] = cfold[256+c] + dbhh[256+c];
        s_bias[32+tid] = cfold[512+c];
        s_bias[48+tid] = dbhh[512+c];
        s_bias[64+tid] = dbhh[c];
        s_bias[80+tid] = dbhh[256+c];
    }
    if (tid < 4){ s_bias[96 + tid] = regb[hb*4 + tid]; s_done[tid] = TSTEPS; }
    __syncthreads();

    // =================== DECODER (g = 128..255) ===================
    for (int i = 0; i < TSTEPS; ++i){
        const int g = TSTEPS + i;
        const unsigned gexp = (unsigned)g;
        const unsigned parb  = (unsigned)(g & 1)*PARU32;
        const unsigned parb2 = (unsigned)((g + 1) & 1)*PARU32;
        const int par = g & 1;

        f32x4 aR[2]={z4,z4}, aZ[2]={z4,z4}, aNi[2]={z4,z4}, aNh[2]={z4,z4};

        probe_wait(hbuf + parb + pr0, hbuf + parb + pr1, gexp);
        u32x4 P[12];
        {
            int ok;
            do {
                #pragma unroll
                for (int ii = 0; ii < 12; ++ii)
                    P[ii] = load_sys_b128(hbuf + parb +
                        (unsigned)((bg*32 + vrow[ii])*ROWG + wv*24 + vgr[ii])*4u);
                waitcnt0();
                int lok = 1;
                #pragma unroll
                for (int ii = 0; ii < 12; ++ii){ regbar4(P[ii]); lok &= (P[ii][3] == gexp); }
                ok = __all(lok);
                if (!ok) __builtin_amdgcn_s_sleep(1);
            } while (!ok);
        }
        // gate: previous step's out-GEMM LDS reads must be done before restaging
        while (__hip_atomic_load(&s_done[2], __ATOMIC_ACQUIRE, __HIP_MEMORY_SCOPE_WORKGROUP) < g) {}
        while (__hip_atomic_load(&s_done[3], __ATOMIC_ACQUIRE, __HIP_MEMORY_SCOPE_WORKGROUP) < g) {}
        #pragma unroll
        for (int ii = 0; ii < 12; ++ii)
            *(u32x4*)(s_h + ((wv*32 + vrow[ii])*24 + vgr[ii])*4) = P[ii];

        #pragma unroll
        for (int m = 0; m < 2; ++m)
            #pragma unroll
            for (int q = 0; q < 2; ++q){
                int gidx = (wv*32 + m*16 + lcol)*24 + (q*2 + (quad>>1))*6 + qp*2;
                s16x8 ah, al; frag_lds(s_h, gidx, qp, ah, al);
                TRIP(aR[m],  ah, al, wfh[0][q], wfl[0][q]);
                TRIP(aZ[m],  ah, al, wfh[1][q], wfl[1][q]);
                TRIP(aNh[m], ah, al, wfh[2][q], wfl[2][q]);
                if (i > 0){
                    TRIP(aR[m],  ah, al, mfh[0][q], mfl[0][q]);
                    TRIP(aZ[m],  ah, al, mfh[1][q], mfl[1][q]);
                    TRIP(aNi[m], ah, al, mfh[2][q], mfl[2][q]);
                }
            }

        #pragma unroll
        for (int m = 0; m < 2; ++m){
            if (wv < 2 && wv == m) continue;
            float* pb = s_part + ((par*4 + wv)*2 + m)*1024 + lane*4;
            *(f32x4*)(pb)      = aR[m];  *(f32x4*)(pb+256) = aZ[m];
            *(f32x4*)(pb+512)  = aNi[m]; *(f32x4*)(pb+768) = aNh[m];
        }
        __hip_atomic_store(&s_flag[wv], g + 1, __ATOMIC_RELEASE, __HIP_MEMORY_SCOPE_WORKGROUP);

        if (wv < 2){
            const int m = wv;
            #pragma unroll
            for (int w = 0; w < 4; ++w){
                if (w == wv) continue;
                while (__hip_atomic_load(&s_flag[w], __ATOMIC_ACQUIRE, __HIP_MEMORY_SCOPE_WORKGROUP) < g + 1) {}
            }
            f32x4 R = aR[m], Z = aZ[m], Ni = aNi[m], Nh = aNh[m];
            #pragma unroll
            for (int w = 0; w < 4; ++w){
                if (w == wv) continue;
                const float* pb = s_part + ((par*4 + w)*2 + m)*1024 + lane*4;
                R += *(const f32x4*)(pb);     Z  += *(const f32x4*)(pb+256);
                Ni += *(const f32x4*)(pb+512); Nh += *(const f32x4*)(pb+768);
            }
            unsigned pk[4];
            #pragma unroll
            for (int j = 0; j < 4; ++j){
                float r, z, n;
                if (i == 0){
                    const float* gp = gi0 + (size_t)(bg*32 + m*16 + quad*4 + j)*G3 + hcol;
                    r = sigmoidf_(R[j] + gp[0]   + s_bias[64+lcol]);
                    z = sigmoidf_(Z[j] + gp[256] + s_bias[80+lcol]);
                    n = tanhf(gp[512] + r*(Nh[j] + s_bias[48+lcol]));
                } else {
                    r = sigmoidf_(R[j] + s_bias[lcol]);
                    z = sigmoidf_(Z[j] + s_bias[16+lcol]);
                    n = tanhf(Ni[j] + s_bias[32+lcol] + r*(Nh[j] + s_bias[48+lcol]));
                }
                float hv = (1.0f - z)*n + z*hold[j];
                unsigned short p1 = bf16_rne(hv);
                unsigned short p0 = bf16_rne(hv - bf16_to_f(p1));
                pk[j] = (((unsigned)p1) << 16) | (unsigned)p0;
                hold[j] = bf16_to_f(p1) + bf16_to_f(p0);
            }
            #pragma unroll
            for (int j = 0; j < 4; ++j){
                unsigned d0 = __shfl(pk[j], quad*16 + ((3*lcol    ) & 15));
                unsigned d1 = __shfl(pk[j], quad*16 + ((3*lcol + 1) & 15));
                unsigned d2 = __shfl(pk[j], quad*16 + ((3*lcol + 2) & 15));
                if (lcol < 6){
                    u32x4 gr = {d0, d1, d2, (unsigned)(g + 1)};
                    store_sys_b128(hbuf + parb2 +
                        (unsigned)((bg*32 + m*16 + quad*4 + j)*ROWG + hb*6 + lcol)*4u, gr);
                }
            }
        } else {
            // out_{i-1} = h^d_i @ regW^T + regb (waves 2,3; off h critical path)
            while (__hip_atomic_load(&s_flag[0], __ATOMIC_ACQUIRE, __HIP_MEMORY_SCOPE_WORKGROUP) < g + 1) {}
            while (__hip_atomic_load(&s_flag[1], __ATOMIC_ACQUIRE, __HIP_MEMORY_SCOPE_WORKGROUP) < g + 1) {}
            const int m = wv - 2;
            s16x8 oah[8], oal[8];
            #pragma unroll
            for (int q8 = 0; q8 < 8; ++q8){
                int w0 = q8*32 + quad*8;
                int gidx = ((w0 >> 6)*32 + m*16 + lcol)*24 + (((w0 & 63) >> 4))*6 + qp*2;
                frag_lds(s_h, gidx, qp, oah[q8], oal[q8]);
            }
            __hip_atomic_store(&s_done[wv], g + 1, __ATOMIC_RELEASE, __HIP_MEMORY_SCOPE_WORKGROUP);
            if (i >= 1){
                float b3 = s_bias[96 + (lcol & 3)];
                f32x4 oa = (f32x4){b3, b3, b3, b3};
                #pragma unroll
                for (int q8 = 0; q8 < 8; ++q8)
                    TRIP(oa, oah[q8], oal[q8], rwh[q8], rwl[q8]);
                if (lcol < 4){
                    #pragma unroll
                    for (int j = 0; j < 4; ++j)
                        out[(size_t)(bg*32 + m*16 + quad*4 + j)*(TSTEPS*Fsz)
                            + (size_t)(i-1)*Fsz + hb*4 + lcol] = oa[j];
                }
            }
        }
    }

    // ---- final pseudo-step: out_{127} from h tag 256 (parity 0) ----
    {
        const unsigned gexp = 2*TSTEPS;
        probe_wait(hbuf + pr0, hbuf + pr1, gexp);
        u32x4 P[12];
        int ok;
        do {
            #pragma unroll
            for (int ii = 0; ii < 12; ++ii)
                P[ii] = load_sys_b128(hbuf +
                    (unsigned)((bg*32 + vrow[ii])*ROWG + wv*24 + vgr[ii])*4u);
            waitcnt0();
            int lok = 1;
            #pragma unroll
            for (int ii = 0; ii < 12; ++ii){ regbar4(P[ii]); lok &= (P[ii][3] == gexp); }
            ok = __all(lok);
            if (!ok) __builtin_amdgcn_s_sleep(1);
        } while (!ok);
        while (__hip_atomic_load(&s_done[2], __ATOMIC_ACQUIRE, __HIP_MEMORY_SCOPE_WORKGROUP) < (int)gexp) {}
        while (__hip_atomic_load(&s_done[3], __ATOMIC_ACQUIRE, __HIP_MEMORY_SCOPE_WORKGROUP) < (int)gexp) {}
        #pragma unroll
        for (int ii = 0; ii < 12; ++ii)
            *(u32x4*)(s_h + ((wv*32 + vrow[ii])*24 + vgr[ii])*4) = P[ii];
        __hip_atomic_store(&s_flag[wv], 2*TSTEPS + 1, __ATOMIC_RELEASE, __HIP_MEMORY_SCOPE_WORKGROUP);
        if (wv >= 2){
            while (__hip_atomic_load(&s_flag[0], __ATOMIC_ACQUIRE, __HIP_MEMORY_SCOPE_WORKGROUP) < 2*TSTEPS + 1) {}
            while (__hip_atomic_load(&s_flag[1], __ATOMIC_ACQUIRE, __HIP_MEMORY_SCOPE_WORKGROUP) < 2*TSTEPS + 1) {}
            const int m = wv - 2;
            float b3 = s_bias[96 + (lcol & 3)];
            f32x4 oa = (f32x4){b3, b3, b3, b3};
            #pragma unroll
            for (int q8 = 0; q8 < 8; ++q8){
                int w0 = q8*32 + quad*8;
                int gidx = ((w0 >> 6)*32 + m*16 + lcol)*24 + (((w0 & 63) >> 4))*6 + qp*2;
                s16x8 ah, al; frag_lds(s_h, gidx, qp, ah, al);
                TRIP(oa, ah, al, rwh[q8], rwl[q8]);
            }
            if (lcol < 4){
                #pragma unroll
                for (int j = 0; j < 4; ++j)
                    out[(size_t)(bg*32 + m*16 + quad*4 + j)*(TSTEPS*Fsz)
                        + (size_t)(TSTEPS-1)*Fsz + hb*4 + lcol] = oa[j];
            }
        }
    }
}

extern "C" void kernel_launch(void* const* d_in, const int* in_sizes, int n_in,
                              void* d_out, int out_size, void* d_ws, size_t ws_size,
                              hipStream_t stream)
{
    (void)in_sizes; (void)n_in; (void)out_size; (void)ws_size;
    const float* x    = (const float*)d_in[0];
    const float* eWih = (const float*)d_in[1];
    const float* eWhh = (const float*)d_in[2];
    const float* ebih = (const float*)d_in[3];
    const float* ebhh = (const float*)d_in[4];
    const float* dWih = (const float*)d_in[5];
    const float* dWhh = (const float*)d_in[6];
    const float* dbih = (const float*)d_in[7];
    const float* dbhh = (const float*)d_in[8];
    const float* regW = (const float*)d_in[9];
    const float* regb = (const float*)d_in[10];
    float* out = (float*)d_out;

    char* base = (char*)d_ws;
    unsigned* hbuf = (unsigned*)base;                     // 2 * 786KB
    float* Mw    = (float*)(base + (size_t)2*PARU32*4);   // 768*256
    float* gi0   = Mw + G3*Hsz;                           // 512*768
    float* cfold = gi0 + Bsz*G3;                          // 768 (+pad)

    // tags are in-data; 0xAA poison never matches g in [1,257] -> no memset needed
    hipLaunchKernelGGL(gru_setup, dim3(2307), dim3(256), 0, stream,
                       x, dWih, dbih, regW, regb, Mw, cfold, gi0);

    hipFuncSetAttribute((const void*)gru_persistent,
                        hipFuncAttributeMaxDynamicSharedMemorySize, SMEM_BYTES);

    void* args[] = { (void*)&x, (void*)&eWih, (void*)&eWhh, (void*)&ebih, (void*)&ebhh,
                     (void*)&dWhh, (void*)&dbhh, (void*)&Mw, (void*)&cfold, (void*)&gi0,
                     (void*)&regW, (void*)&regb, (void*)&hbuf, (void*)&out };
    hipError_t rc = hipLaunchCooperativeKernel((const void*)gru_persistent,
                                               dim3(NBLK), dim3(NTHR), args,
                                               SMEM_BYTES, stream);
    if (rc != hipSuccess) {
        hipLaunchKernelGGL(gru_persistent, dim3(NBLK), dim3(NTHR), SMEM_BYTES, stream,
                           x, eWih, eWhh, ebih, ebhh, dWhh, dbhh, Mw, cfold, gi0,
                           regW, regb, hbuf, out);
    }
}